// Round 8
// baseline (1340.097 us; speedup 1.0000x reference)
//
#include <hip/hip_runtime.h>
#include <math.h>

#define TS 10
#define TD 128
#define TE 64
#define BT 4
#define NTHR 256
#define HSTR 128          // Hs row stride: all accesses broadcast-row or lane-consecutive -> no pad needed
#define QSTR 68           // Q/K/Vd/G/t row stride: padded so logits' multi-row reads spread banks

#define HS_FLOATS (4*TS*HSTR)          // 5120
#define BUFS_FLOATS (4*3*TS*QSTR)      // 8160 (4 waves x {Q,K,V} x 10 rows)
#define P_FLOATS (4*TS*12)             // 480
#define LDS_FLOATS (HS_FLOATS + BUFS_FLOATS + P_FLOATS)   // 13760 -> 55040 B (2 WG/CU)

#define INVSQRT10 0.31622776601683794f

typedef float v2f __attribute__((ext_vector_type(2)));

// Packed FMA via VOP3P op_sel (bit-identical IEEE fp32 fma), R7-proven:
//   PKFMA_LO: acc += a.lo * (w0,w1) ;  PKFMA_HI: acc += a.hi * (w0,w1)
#define PKFMA_LO(acc_, ap_, wp_) \
    asm("v_pk_fma_f32 %0, %1, %2, %0 op_sel:[0,0,0] op_sel_hi:[0,1,1]" \
        : "+v"(acc_) : "v"(ap_), "v"(wp_))
#define PKFMA_HI(acc_, ap_, wp_) \
    asm("v_pk_fma_f32 %0, %1, %2, %0 op_sel:[1,0,0] op_sel_hi:[1,1,1]" \
        : "+v"(acc_) : "v"(ap_), "v"(wp_))

// Wave-synchronous LDS fence: all prior DS ops retired (lgkmcnt counts LDS ops,
// write-retire == LDS-visible) + full compiler memory/scheduling barrier.
// Cross-lane LDS communication WITHIN one wave needs exactly this, not s_barrier.
#define WSYNC() do { __builtin_amdgcn_wave_barrier(); \
    asm volatile("s_waitcnt lgkmcnt(0)" ::: "memory"); \
    __builtin_amdgcn_wave_barrier(); } while (0)

// ---------------- pre-kernel: POS table + fused quesout2@UL_w --------------
// ws layout: [0,1280) POS[10][128]; [1280,3840) P2[n][c][k] (10x4x64):
//   P2[n][c][k] = sum_d quesout2[n][k][d] * UL_w[d][c]
// so out[b][n][c] = sum_k t2[b][n][k] * P2[n][c][k]  (contiguous-k dots).
__global__ void pre_kernel(float* __restrict__ ws,
                           const float* __restrict__ qout2,
                           const float* __restrict__ UL_w) {
    int tid = threadIdx.x;
    for (int idx = tid; idx < TS * TD; idx += 256) {
        int n = idx / TD, d = idx % TD;
        int j = d >> 1;
        double ang = (double)n / pow(1000.0, 2.0 * (double)j / (double)TD);
        double v = (d & 1) ? cos(ang) : sin(ang);
        ws[idx] = (float)v;
    }
    for (int idx = tid; idx < TS * 4 * TE; idx += 256) {
        int n = idx >> 8, r = idx & 255, c = r >> 6, k = r & 63;
        const float* qp = qout2 + ((size_t)n * TE + k) * TD;
        float acc = 0.f;
        for (int d = 0; d < TD; d += 4) {
            float4 q4 = *(const float4*)(qp + d);
            acc = fmaf(q4.x, UL_w[(d + 0) * 4 + c], acc);
            acc = fmaf(q4.y, UL_w[(d + 1) * 4 + c], acc);
            acc = fmaf(q4.z, UL_w[(d + 2) * 4 + c], acc);
            acc = fmaf(q4.w, UL_w[(d + 3) * 4 + c], acc);
        }
        ws[TS * TD + idx] = acc;
    }
}

// ---------------- M-row x C-col fp32 GEMM tile -------------------------------
// OUT[m][c] (+)= scale * sum_k A[row(m)+k] * W[k*ws+c]. A,O in LDS; W global.
// Light 4-k double-buffer (latency hidden by 8 independent waves/CU, not ILP).
// C=2 (v2f W) or C%4==0 (float4 W); op_sel packed FMAs, zero broadcast movs.
// K multiple of 8, >=16. row(m) = (m/SPLIT)*aHi + (m%SPLIT)*aLo.
template <int M, int SPLIT, int C, int K, bool ADD>
__device__ __forceinline__ void gemm_f32(
    const float* __restrict__ Ap, int a0, int aHi, int aLo,
    const float* __restrict__ W, int ws,
    float* __restrict__ Op, int o0, int oHi, int oLo,
    float scale)
{
    static_assert(C == 2 || (C % 4 == 0), "C must be 2 or multiple of 4");
    static_assert(K % 8 == 0 && K >= 16, "K must be multiple of 8, >=16");
    constexpr int CP = C / 2;
    v2f acc[M][CP];
#pragma unroll
    for (int m = 0; m < M; m++)
#pragma unroll
        for (int p = 0; p < CP; p++) acc[m][p] = (v2f)(0.f);

    float4 aR0[M], aR1[M];
    v2f wR0[4 * CP], wR1[4 * CP];
    const float* ap = Ap + a0;
    const float* wp = W;

    auto loadW = [&](v2f* wR, const float* w) {
#pragma unroll
        for (int kk = 0; kk < 4; kk++) {
            if constexpr (C % 4 == 0) {
#pragma unroll
                for (int cg = 0; cg < C / 4; cg++) {
                    float4 t = *(const float4*)(w + kk * ws + cg * 4);
                    wR[kk * CP + 2 * cg + 0] = ((const v2f*)&t)[0];
                    wR[kk * CP + 2 * cg + 1] = ((const v2f*)&t)[1];
                }
            } else {
                wR[kk * CP] = *(const v2f*)(w + kk * ws);
            }
        }
    };
    auto loadA = [&](float4* aR, const float* a) {
#pragma unroll
        for (int m = 0; m < M; m++)
            aR[m] = *(const float4*)(a + (m / SPLIT) * aHi + (m % SPLIT) * aLo);
    };
    auto compute = [&](const float4* aR, const v2f* wR) {
#pragma unroll
        for (int m = 0; m < M; m++) {
            const v2f* ap2 = (const v2f*)&aR[m];   // (a0,a1),(a2,a3)
#pragma unroll
            for (int kp = 0; kp < 2; kp++) {
#pragma unroll
                for (int p = 0; p < CP; p++) {
                    PKFMA_LO(acc[m][p], ap2[kp], wR[(2 * kp + 0) * CP + p]);
                    PKFMA_HI(acc[m][p], ap2[kp], wR[(2 * kp + 1) * CP + p]);
                }
            }
        }
    };

    loadW(wR0, wp); loadA(aR0, ap);
#pragma unroll 1
    for (int k = 0; k + 8 < K; k += 8) {
        loadW(wR1, wp + 4 * ws); loadA(aR1, ap + 4);
        compute(aR0, wR0);
        wp += 8 * ws; ap += 8;
        loadW(wR0, wp); loadA(aR0, ap);
        compute(aR1, wR1);
    }
    loadW(wR1, wp + 4 * ws); loadA(aR1, ap + 4);
    compute(aR0, wR0);
    compute(aR1, wR1);

    v2f s2; s2.x = scale; s2.y = scale;
#pragma unroll
    for (int m = 0; m < M; m++) {
        float* op = Op + o0 + (m / SPLIT) * oHi + (m % SPLIT) * oLo;
        if constexpr (C % 4 == 0) {
#pragma unroll
            for (int cg = 0; cg < C / 4; cg++) {
                float4 r;
                v2f* rp = (v2f*)&r;
                if constexpr (ADD) {
                    float4 v = *(float4*)(op + cg * 4);
                    const v2f* vp = (const v2f*)&v;
                    rp[0] = s2 * acc[m][cg * 2 + 0] + vp[0];
                    rp[1] = s2 * acc[m][cg * 2 + 1] + vp[1];
                } else {
                    rp[0] = s2 * acc[m][cg * 2 + 0];
                    rp[1] = s2 * acc[m][cg * 2 + 1];
                }
                *(float4*)(op + cg * 4) = r;
            }
        } else {
            v2f r;
            if constexpr (ADD) { r = s2 * acc[m][0] + *(const v2f*)op; }
            else               { r = s2 * acc[m][0]; }
            *(v2f*)op = r;
        }
    }
}

// ---------------- fused kernel ----------------------------------------------
// R8 restructure: BT=4, wave-per-batch attention with ZERO barriers inside the
// attention block (wave-synchronous LDS: WSYNC only). Cooperative ques phases
// (M=4 batch amortization of quesin/quesout weights) keep __syncthreads:
// 6 barriers/kernel vs 26 before. 55.04 KB LDS -> 2 WG/CU = 8 independent
// wave streams/CU during attention. quesout2@UL_w pre-fused (-8% MACs).
extern "C" __global__ __launch_bounds__(NTHR, 2)
void trans_fused(const float* __restrict__ x,
                 const float* __restrict__ L_w, const float* __restrict__ UL_w,
                 const float* __restrict__ WQ,  const float* __restrict__ WK,
                 const float* __restrict__ WVd, const float* __restrict__ WVu,
                 const float* __restrict__ WQ2, const float* __restrict__ WK2,
                 const float* __restrict__ WVd2,const float* __restrict__ WVu2,
                 const float* __restrict__ qin1,const float* __restrict__ qout1,
                 const float* __restrict__ qin2,const float* __restrict__ qout2,
                 const float* __restrict__ POSb, float* __restrict__ out)
{
    extern __shared__ float lds[];
    float* Hs   = lds;                     // [40][HSTR], row = b*10 + n
    float* Bufs = lds + HS_FLOATS;         // 4 waves x {Q,K,V}[10][QSTR]
    float* Pb   = Bufs + BUFS_FLOATS;      // [4][10][12]
    float* Tb   = Bufs;                    // t[40][QSTR] alias (ques phases only)

    const int tid = threadIdx.x;
    const int w   = tid >> 6;              // wave id == batch within WG
    const int l   = tid & 63;
    const int vtid = (tid + ((blockIdx.x & 3) << 6)) & 255;  // coop-phase rotation
    const int gb0 = blockIdx.x * BT;
    const float* P2 = POSb + TS * TD;      // fused quesout2@UL_w [10][4][64]

    float* QB = Bufs + w * (3 * TS * QSTR);
    float* KB = QB + TS * QSTR;
    float* VB = KB + TS * QSTR;
    float* PW = Pb + w * (TS * 12);

    // ---- Phase 0 (per-wave): Hs rows of own batch = x@L_w + POS ----
    {
        const float* xb = x + (size_t)(gb0 + w) * TS * 4;
        for (int t4 = l; t4 < TS * 32; t4 += 64) {   // 320 float4 groups
            int n = t4 >> 5, dg = (t4 & 31) << 2;
            float4 xv = *(const float4*)(xb + n * 4);
            const float* xf = (const float*)&xv;
            float4 p4 = *(const float4*)(POSb + n * TD + dg);
            v2f a0v = ((const v2f*)&p4)[0], a1v = ((const v2f*)&p4)[1];
#pragma unroll
            for (int c = 0; c < 4; c++) {
                float4 lw = *(const float4*)(L_w + c * TD + dg);
                v2f xbv; xbv.x = xf[c]; xbv.y = xf[c];
                a0v = xbv * ((const v2f*)&lw)[0] + a0v;
                a1v = xbv * ((const v2f*)&lw)[1] + a1v;
            }
            float4 r4;
            ((v2f*)&r4)[0] = a0v; ((v2f*)&r4)[1] = a1v;
            *(float4*)(Hs + (w * TS + n) * HSTR + dg) = r4;
        }
    }
    WSYNC();

    for (int layer = 0; layer < 2; ++layer) {
        const float* pWQ  = layer ? WQ2  : WQ;
        const float* pWK  = layer ? WK2  : WK;
        const float* pWVd = layer ? WVd2 : WVd;
        const float* pWVu = layer ? WVu2 : WVu;
        const float* pqin = layer ? qin2 : qin1;

        // ================= attention: per-wave, barrier-free =================
        {
            // ---- QKV: 3 x gemm, tasks = rg(2) x cg2(32) = 64 lanes ----
            int rg = l >> 5, cg2 = l & 31;
            int aoff = (w * TS + rg * 5) * HSTR;
            int ooff = (rg * 5) * QSTR + cg2 * 2;
            gemm_f32<5, 5, 2, TD, false>(Hs, aoff, 0, HSTR, pWQ  + cg2 * 2, TE, QB, ooff, 0, QSTR, 1.f);
            gemm_f32<5, 5, 2, TD, false>(Hs, aoff, 0, HSTR, pWK  + cg2 * 2, TE, KB, ooff, 0, QSTR, 1.f);
            gemm_f32<5, 5, 2, TD, false>(Hs, aoff, 0, HSTR, pWVd + cg2 * 2, TE, VB, ooff, 0, QSTR, 1.f);
            WSYNC();

            // ---- logits: 55 (i, j<=i) pairs, one lane each ----
            if (l < 55) {
                int i = 0, base = 0, pr = l;
                while (pr >= base + i + 1) { base += i + 1; i++; }
                int j = pr - base;
                const float* qr = QB + i * QSTR;
                const float* kr = KB + j * QSTR;
                v2f s0 = (v2f)(0.f), s1 = (v2f)(0.f);
                for (int e = 0; e < TE; e += 8) {
                    float4 qa = *(const float4*)(qr + e);
                    float4 ka = *(const float4*)(kr + e);
                    float4 qc = *(const float4*)(qr + e + 4);
                    float4 kc = *(const float4*)(kr + e + 4);
                    s0 = ((const v2f*)&qa)[0] * ((const v2f*)&ka)[0] + s0;
                    s1 = ((const v2f*)&qa)[1] * ((const v2f*)&ka)[1] + s1;
                    s0 = ((const v2f*)&qc)[0] * ((const v2f*)&kc)[0] + s0;
                    s1 = ((const v2f*)&qc)[1] * ((const v2f*)&kc)[1] + s1;
                }
                PW[i * 12 + j] = (s0.x + s0.y) + (s1.x + s1.y);
            }
            WSYNC();

            // ---- softmax over keys j<=i (fp32, matches reference) ----
            if (l < TS) {
                float* pr = PW + l * 12;
                float m = pr[0];
#pragma unroll
                for (int j = 1; j < TS; j++) if (j <= l) m = fmaxf(m, pr[j]);
                float sum = 0.f;
#pragma unroll
                for (int j = 0; j < TS; j++) if (j <= l) { float e = expf(pr[j] - m); pr[j] = e; sum += e; }
#pragma unroll
                for (int j = 0; j < TS; j++) pr[j] = (j <= l) ? pr[j] / sum : 0.f;
            }
            WSYNC();

            // ---- G[q][e] = sum_k P[q][k] * Vd[k][e]; into QB (Q dead) ----
            {
                int qh = l >> 5, e2 = l & 31;
#pragma unroll
                for (int q = 0; q < 5; q++) {
                    int row = qh * 5 + q;
                    v2f acc = (v2f)(0.f);
#pragma unroll
                    for (int kp = 0; kp < 5; kp++) {
                        v2f pp = *(const v2f*)(PW + row * 12 + 2 * kp);
                        v2f v0 = *(const v2f*)(VB + (2 * kp + 0) * QSTR + e2 * 2);
                        v2f v1 = *(const v2f*)(VB + (2 * kp + 1) * QSTR + e2 * 2);
                        PKFMA_LO(acc, pp, v0);
                        PKFMA_HI(acc, pp, v1);
                    }
                    *(v2f*)(QB + row * QSTR + e2 * 2) = acc;
                }
            }
            WSYNC();

            // ---- DE: Hs(own rows) += invsqrt10 * G @ WVu; rg(2) x cg4(32) ----
            {
                int rgd = l >> 5, cgd = l & 31;
                gemm_f32<5, 5, 4, TE, true>(
                    QB, (rgd * 5) * QSTR, 0, QSTR,
                    pWVu + cgd * 4, TD,
                    Hs, (w * TS + rgd * 5) * HSTR + cgd * 4, 0, HSTR,
                    INVSQRT10);
            }
        }
        __syncthreads();

        // ---- quesin (coop): t = Hs @ quesin[n]; 160 = n(10) x cg4(16), M=4 ----
        if (vtid < 160) {
            int n = vtid >> 4, cg = vtid & 15;
            gemm_f32<4, 1, 4, TD, false>(
                Hs, n * HSTR, TS * HSTR, 0,
                pqin + (size_t)n * TD * TE + cg * 4, TE,
                Tb, n * QSTR + cg * 4, TS * QSTR, 0, 1.f);
        }
        __syncthreads();

        if (layer == 0) {
            // ---- quesout1 (coop): Hs = t @ quesout1[n]; 320 = n(10) x cg4(32) ----
            for (int task = vtid; task < 320; task += NTHR) {
                int n = task >> 5, cg = task & 31;
                gemm_f32<4, 1, 4, TE, false>(
                    Tb, n * QSTR, TS * QSTR, 0,
                    qout1 + (size_t)n * TE * TD + cg * 4, TD,
                    Hs, n * HSTR + cg * 4, TS * HSTR, 0, 1.f);
            }
            __syncthreads();
        } else {
            // ---- fused out: out[b][n][c] = t row . P2[n][c][:] (K=64) ----
            if (vtid < 160) {
                int r = vtid >> 2, c = vtid & 3;
                int b = r / 10, n = r - b * 10;
                const float* tr = Tb + r * QSTR;
                const float* pr = P2 + (n * 4 + c) * TE;
                float acc = 0.f;
                for (int k = 0; k < TE; k += 4) {
                    float4 t4 = *(const float4*)(tr + k);
                    float4 p4 = *(const float4*)(pr + k);
                    acc = fmaf(t4.x, p4.x, acc);
                    acc = fmaf(t4.y, p4.y, acc);
                    acc = fmaf(t4.z, p4.z, acc);
                    acc = fmaf(t4.w, p4.w, acc);
                }
                out[((size_t)(gb0 + b) * TS + n) * 4 + c] = acc;
            }
        }
    } // layer
}

// ---------------- host launch -----------------------------------------------
extern "C" void kernel_launch(void* const* d_in, const int* in_sizes, int n_in,
                              void* d_out, int out_size, void* d_ws, size_t ws_size,
                              hipStream_t stream) {
    const float* x    = (const float*)d_in[0];
    const float* L_w  = (const float*)d_in[1];
    const float* UL_w = (const float*)d_in[2];
    const float* WQ   = (const float*)d_in[3];
    const float* WK   = (const float*)d_in[4];
    const float* WVd  = (const float*)d_in[5];
    const float* WVu  = (const float*)d_in[6];
    const float* WQ2  = (const float*)d_in[7];
    const float* WK2  = (const float*)d_in[8];
    const float* WVd2 = (const float*)d_in[9];
    const float* WVu2 = (const float*)d_in[10];
    const float* qin1 = (const float*)d_in[11];
    const float* qout1= (const float*)d_in[12];
    const float* qin2 = (const float*)d_in[13];
    const float* qout2= (const float*)d_in[14];
    float* out = (float*)d_out;
    float* POSb = (float*)d_ws;

    int B = in_sizes[0] / (TS * 4);
    size_t lds_bytes = (size_t)LDS_FLOATS * sizeof(float);

    (void)hipFuncSetAttribute((const void*)trans_fused,
                              hipFuncAttributeMaxDynamicSharedMemorySize,
                              (int)lds_bytes);

    pre_kernel<<<dim3(1), dim3(256), 0, stream>>>(POSb, qout2, UL_w);
    trans_fused<<<dim3(B / BT), dim3(NTHR), lds_bytes, stream>>>(
        x, L_w, UL_w, WQ, WK, WVd, WVu, WQ2, WK2, WVd2, WVu2,
        qin1, qout1, qin2, qout2, POSb, out);
}